// Round 17
// baseline (149.732 us; speedup 1.0000x reference)
//
#include <hip/hip_runtime.h>

typedef unsigned short u16;
typedef unsigned int u32;
typedef u16 u16x8 __attribute__((ext_vector_type(8)));
typedef u16 u16x4 __attribute__((ext_vector_type(4)));
typedef u32 u32x4 __attribute__((ext_vector_type(4)));
typedef float f32x4 __attribute__((ext_vector_type(4)));
typedef float f32x16 __attribute__((ext_vector_type(16)));
typedef __bf16 bf16x8 __attribute__((ext_vector_type(8)));

#define SCALE_L2E 0.51006972864f  /* 64^-0.25 * log2(e), folded into Q rope */
#define LAMBDA_INIT 0.7836057665316245f
#define ONE_MINUS_LI 0.21639423346837554f

__device__ __forceinline__ u16 b16(float f) {
  return __builtin_bit_cast(u16, (__bf16)f);
}
__device__ __forceinline__ float bf2f(u16 h) {
  unsigned u = ((unsigned)h) << 16;
  return __builtin_bit_cast(float, u);
}
__device__ __forceinline__ u32 pk2(float lo, float hi) {
  return (u32)b16(lo) | ((u32)b16(hi) << 16);
}
__device__ __forceinline__ f32x4 mfma16(bf16x8 a, bf16x8 b, f32x4 c) {
  return __builtin_amdgcn_mfma_f32_16x16x32_bf16(a, b, c, 0, 0, 0);
}
__device__ __forceinline__ f32x16 mfma32(bf16x8 a, bf16x8 b, f32x16 c) {
  return __builtin_amdgcn_mfma_f32_32x32x16_bf16(a, b, c, 0, 0, 0);
}
// v_permlane32_swap: only with operands holding DISTINCT values (same-value
// operands may be register-coalesced -> degenerate half-rotate; r7 bug).
// NOTE (r13): extra mfma consumers of permlane-built P broke numerics; do not retry.
// NOTE (r16): cross-iteration K-register prefetch pipeline broke numerics; this
// version loads K fragments at tile start (no carry, no guards).
__device__ __forceinline__ void plswapu(u32& a, u32& b) {
  asm("v_permlane32_swap_b32 %0, %1" : "+v"(a), "+v"(b));
}
// async global->LDS, 16B/lane; LDS dest = wave-uniform base + lane*16
__device__ __forceinline__ void gld16(const void* g, void* l) {
  __builtin_amdgcn_global_load_lds(
      (const __attribute__((address_space(1))) unsigned int*)g,
      (__attribute__((address_space(3))) unsigned int*)l, 16, 0, 0);
}

// ---------------- fused prep: f32->bf16 converts + RoPE table + lambda ----------------
__global__ void prep_kernel(const float* __restrict__ x, const float* __restrict__ Wq,
                            const float* __restrict__ Wk, const float* __restrict__ Wv,
                            const float* __restrict__ Wo,
                            const float* __restrict__ lq1, const float* __restrict__ lk1,
                            const float* __restrict__ lq2, const float* __restrict__ lk2,
                            u16* __restrict__ xb, u16* __restrict__ wqb, u16* __restrict__ wkb,
                            u16* __restrict__ wvb, u16* __restrict__ wob,
                            float* __restrict__ cosT, float* __restrict__ sinT,
                            float* __restrict__ lamp) {
  const int bid = blockIdx.x, tid = threadIdx.x;
  if (bid < 8192) {
    const float* src; u16* dst; int off;
    if (bid < 4096) { src = x; dst = xb; off = bid; }
    else {
      const int wsel = (bid - 4096) >> 10;
      off = (bid - 4096) & 1023;
      src = wsel == 0 ? Wq : wsel == 1 ? Wk : wsel == 2 ? Wv : Wo;
      dst = wsel == 0 ? wqb : wsel == 1 ? wkb : wsel == 2 ? wvb : wob;
    }
    const size_t i = (size_t)off * 256 + tid;
    f32x4 v = *(const f32x4*)(src + i * 4);
    u16x4 o;
    o[0] = b16(v[0]); o[1] = b16(v[1]); o[2] = b16(v[2]); o[3] = b16(v[3]);
    *(u16x4*)(dst + i * 4) = o;
  } else if (bid < 8448) {
    const int i = (bid - 8192) * 256 + tid;   // 0..65535 = [s=2048][fi=32]
    const int fi = i & 31, t = i >> 5;
    float invf = expf(-(float)fi * 0.2878231366242558f);
    float f = (float)t * invf;
    cosT[i] = cosf(f);
    sinT[i] = sinf(f);
  } else if (tid < 64) {
    int l = tid;
    float a = lq1[l] * lk1[l];
    float bb = lq2[l] * lk2[l];
#pragma unroll
    for (int m = 1; m < 64; m <<= 1) {
      a += __shfl_xor(a, m);
      bb += __shfl_xor(bb, m);
    }
    if (l == 0) lamp[0] = expf(a) - expf(bb) + LAMBDA_INIT;
  }
}

// ---------------- GEMM C = A @ B^T via global_load_lds + XOR swizzle ----------------
// MODE 0: bf16 row-major out; 1: f32 row-major out; 2: bf16 V-transposed out
//   (MODE 2: Vt[(b*8 + col/128)*128 + col%128][s], s = global row)
// MODE 3: bf16 row-major out with fused interleaved RoPE (pair = col^1 = lane c^1,
//   partner value via __shfl_xor on f32 acc; cos/sin scaled by ropeScale).
template<int MODE, int BN>
__device__ __forceinline__ void gemm_body(const u16* __restrict__ A, const u16* __restrict__ Bm,
                                          void* __restrict__ C, int M, int N, int K,
                                          const float* __restrict__ cosT,
                                          const float* __restrict__ sinT, float ropeScale) {
  __shared__ __align__(1024) u16 As[128][64];
  __shared__ __align__(1024) u16 Bs[BN][64];
  constexpr int NF = BN / 32;          // n-frags per wave
  constexpr int JL = (16 + BN / 8) / 4; // staged chunks per wave
  const int tid = threadIdx.x;
  const int lane = tid & 63, wid = tid >> 6;
  const int wr = wid >> 1, wc = wid & 1;
  const int c = lane & 15, g = lane >> 4;
  const int bm = blockIdx.x * 128, bn = blockIdx.y * BN;
  const int srow = lane >> 3;          // 0..7 (row within 8-row chunk)
  const int scol = lane & 7;
  f32x4 acc[4][NF];
#pragma unroll
  for (int m = 0; m < 4; ++m)
#pragma unroll
    for (int n = 0; n < NF; ++n) acc[m][n] = (f32x4){0.f, 0.f, 0.f, 0.f};

  for (int k0 = 0; k0 < K; k0 += 64) {
#pragma unroll
    for (int j = 0; j < JL; ++j) {
      const int cid = wid * JL + j;       // wave-uniform chunk id
      if (cid < 16) {
        const int row = (cid << 3) + srow;
        gld16(A + (size_t)(bm + row) * K + k0 + ((scol ^ srow) << 3), &As[cid << 3][0]);
      } else {
        const int ch = cid - 16;
        const int row = (ch << 3) + srow;
        gld16(Bm + (size_t)(bn + row) * K + k0 + ((scol ^ srow) << 3), &Bs[ch << 3][0]);
      }
    }
    __syncthreads();
#pragma unroll
    for (int kk = 0; kk < 2; ++kk) {
      bf16x8 af[4], bfm[NF];
#pragma unroll
      for (int m = 0; m < 4; ++m)
        af[m] = __builtin_bit_cast(bf16x8,
            *(const u16x8*)(&As[wr * 64 + m * 16 + c][(((kk << 2) | g) ^ (c & 7)) << 3]));
#pragma unroll
      for (int n = 0; n < NF; ++n)
        bfm[n] = __builtin_bit_cast(bf16x8,
            *(const u16x8*)(&Bs[wc * (BN / 2) + n * 16 + c][(((kk << 2) | g) ^ (c & 7)) << 3]));
#pragma unroll
      for (int m = 0; m < 4; ++m)
#pragma unroll
        for (int n = 0; n < NF; ++n)
          acc[m][n] = mfma16(af[m], bfm[n], acc[m][n]);
    }
    __syncthreads();
  }
#pragma unroll
  for (int m = 0; m < 4; ++m)
#pragma unroll
    for (int n = 0; n < NF; ++n) {
      const int col = bn + wc * (BN / 2) + n * 16 + c;
      const int row0 = bm + wr * 64 + m * 16 + g * 4;
      if constexpr (MODE == 2) {
        const int bI = row0 >> 11, s0 = row0 & 2047;
        u16x4 pk;
#pragma unroll
        for (int r = 0; r < 4; ++r) pk[r] = b16(acc[m][n][r]);
        *(u16x4*)((u16*)C + ((size_t)(bI * 8 + (col >> 7)) * 128 + (col & 127)) * 2048 + s0) = pk;
      } else if constexpr (MODE == 3) {
        const int dcol = col & 63;
        const int fi = dcol >> 1;
#pragma unroll
        for (int r = 0; r < 4; ++r) {
          float v = acc[m][n][r];
          float vp = __shfl_xor(v, 1);          // partner col^1 = lane c^1
          const int s = (row0 + r) & 2047;
          float cc = cosT[s * 32 + fi] * ropeScale;
          float sn = sinT[s * 32 + fi] * ropeScale;
          float ov = (dcol & 1) ? (v * cc + vp * sn) : (v * cc - vp * sn);
          ((u16*)C)[(size_t)(row0 + r) * N + col] = b16(ov);
        }
      } else {
#pragma unroll
        for (int r = 0; r < 4; ++r) {
          if constexpr (MODE == 1) ((float*)C)[(size_t)(row0 + r) * N + col] = acc[m][n][r];
          else ((u16*)C)[(size_t)(row0 + r) * N + col] = b16(acc[m][n][r]);
        }
      }
    }
}

__global__ __launch_bounds__(256) void gemm_qkv_kernel(
    const u16* __restrict__ A,
    const u16* __restrict__ B0, const u16* __restrict__ B1, const u16* __restrict__ B2,
    u16* __restrict__ C0, u16* __restrict__ C1, u16* __restrict__ C2,
    const float* __restrict__ cosT, const float* __restrict__ sinT) {
  if (blockIdx.z == 0)
    gemm_body<3, 128>(A, B0, C0, 4096, 1024, 1024, cosT, sinT, SCALE_L2E);  // Q: rope+scale
  else if (blockIdx.z == 1)
    gemm_body<3, 128>(A, B1, C1, 4096, 1024, 1024, cosT, sinT, 1.0f);       // K: rope
  else
    gemm_body<2, 128>(A, B2, C2, 4096, 1024, 1024, nullptr, nullptr, 0.f);  // V: transpose
}

__global__ __launch_bounds__(256) void gemm_f32_kernel(const u16* __restrict__ A,
                                                       const u16* __restrict__ Bm,
                                                       float* __restrict__ C) {
  gemm_body<1, 64>(A, Bm, C, 4096, 1024, 1024, nullptr, nullptr, 0.f);
}

// ---------------- fused flash diff-attention (v14: K-direct, de-pipelined) ----------------
// v12 base (KVBLK=64, 32x32 MFMA, in-reg P, max-free log2 softmax). K fragments
// loaded from global at TILE START (contiguous 16B/lane; L2-resident), used
// immediately — no cross-iteration register carry, no prefetch guards (the r16
// mechanism). V-only LDS dbuf (2x16KB). L cross-half merge deferred to epilogue.
#define STAGE_TO(NB)                                                           \
  {                                                                            \
    _Pragma("unroll")                                                          \
    for (int j = 0; j < 4; ++j) {                                              \
      const int ch = (wid << 2) | j;                                           \
      gld16(sp[j], smem + (NB) + ch * 1024);                                   \
      sp[j] += 64;                                                             \
    }                                                                          \
  }

#define PACK4(PE, PA0, PA1)                                                    \
  {                                                                            \
    u32 w0 = pk2(PE[0], PE[1]),   w1 = pk2(PE[2], PE[3]);                      \
    u32 w2 = pk2(PE[4], PE[5]),   w3 = pk2(PE[6], PE[7]);                      \
    u32 w4 = pk2(PE[8], PE[9]),   w5 = pk2(PE[10], PE[11]);                    \
    u32 w6 = pk2(PE[12], PE[13]), w7 = pk2(PE[14], PE[15]);                    \
    plswapu(w0, w2); plswapu(w1, w3);                                          \
    plswapu(w4, w6); plswapu(w5, w7);                                          \
    u32x4 pw0, pw1;                                                            \
    pw0[0] = w0; pw0[1] = w1; pw0[2] = w2; pw0[3] = w3;                        \
    pw1[0] = w4; pw1[1] = w5; pw1[2] = w6; pw1[3] = w7;                        \
    PA0 = __builtin_bit_cast(bf16x8, pw0);                                     \
    PA1 = __builtin_bit_cast(bf16x8, pw1);                                     \
  }

#define TILE(CB, NB, T)                                                        \
  {                                                                            \
    bf16x8 kf[8];                                                              \
    _Pragma("unroll")                                                          \
    for (int q = 0; q < 8; ++q)                                                \
      kf[q] = __builtin_bit_cast(bf16x8,                                       \
          *(const u16x8*)(kl + (size_t)(T) * 65536 + (q >> 2) * 32768 +        \
                          (q & 3) * 16));                                      \
    if ((T) < 31) STAGE_TO(NB);                                                \
    f32x16 sacc[2];                                                            \
    _Pragma("unroll")                                                          \
    for (int s32 = 0; s32 < 2; ++s32) {                                        \
      sacc[s32] = mfma32(kf[s32 * 4], qf[0], z16);                             \
      _Pragma("unroll")                                                        \
      for (int ds = 1; ds < 4; ++ds)                                           \
        sacc[s32] = mfma32(kf[s32 * 4 + ds], qf[ds], sacc[s32]);               \
    }                                                                          \
    float pe0[16], pe1[16];                                                    \
    float sA = 0.f, sB = 0.f, sC = 0.f, sD = 0.f;                              \
    _Pragma("unroll")                                                          \
    for (int i = 0; i < 16; i += 2) {                                          \
      pe0[i] = __builtin_amdgcn_exp2f(sacc[0][i]);                             \
      sA += pe0[i];                                                            \
      pe0[i + 1] = __builtin_amdgcn_exp2f(sacc[0][i + 1]);                     \
      sB += pe0[i + 1];                                                        \
      pe1[i] = __builtin_amdgcn_exp2f(sacc[1][i]);                             \
      sC += pe1[i];                                                            \
      pe1[i + 1] = __builtin_amdgcn_exp2f(sacc[1][i + 1]);                     \
      sD += pe1[i + 1];                                                        \
    }                                                                          \
    L_r += (sA + sB) + (sC + sD);                                              \
    bf16x8 pa[4];                                                              \
    PACK4(pe0, pa[0], pa[1]);                                                  \
    PACK4(pe1, pa[2], pa[3]);                                                  \
    _Pragma("unroll")                                                          \
    for (int dd = 0; dd < 4; ++dd) {                                           \
      _Pragma("unroll")                                                        \
      for (int ks = 0; ks < 4; ++ks) {                                         \
        bf16x8 vf = __builtin_bit_cast(bf16x8,                                 \
            *(const u16x8*)(smem + (CB) + dd * 4096 + vv[ks]));                \
        acc[dd] = mfma32(pa[ks], vf, acc[dd]);                                 \
      }                                                                        \
    }                                                                          \
    __syncthreads();                                                           \
  }

__global__ __launch_bounds__(256, 2) void attn_kernel(
    const u16* __restrict__ Qb, const u16* __restrict__ Kb, const u16* __restrict__ Vt,
    const float* __restrict__ lamp, const float* __restrict__ lnw, const float* __restrict__ lnb,
    u16* __restrict__ Oc) {
  // main loop: V dbuf [128][64] u16 at 0 / 16384 (32KB total)
  // epilogue overlay: O[2][64][128] u16 (32KB) @ 0 + L[2][64] f32 @ +32768
  __shared__ __align__(1024) char smem[33280];
  const int tid = threadIdx.x;
  const int lane = tid & 63;
  const int wid = tid >> 6;            // 0..3
  const int c32 = lane & 31, hi = lane >> 5;
  const int p = wid >> 1, sg = wid & 1;

  const int B = blockIdx.x;
  const int xcd = B & 7, bidx = B >> 3;
  const int bh = xcd * 2 + (bidx >> 5);
  const int qt = bidx & 31;
  const int b = bh >> 3, h = bh & 7;
  const int head2 = 2 * h + p;

  // Q fragments: lane owns q-row qrow; qf[ds] covers d = ds*16 + hi*8 .. +8
  const int qrow = qt * 64 + sg * 32 + c32;
  bf16x8 qf[4];
#pragma unroll
  for (int ds = 0; ds < 4; ++ds)
    qf[ds] = __builtin_bit_cast(bf16x8,
        *(const u16x8*)(Qb + ((size_t)(b * 2048 + qrow) * 16 + head2) * 64 + ds * 16 + hi * 8));

  // per-lane K global base (key row c32 of this (b, head2)); tile stride 65536 u16
  const u16* kl = Kb + ((size_t)(b * 2048 + c32) * 16 + head2) * 64 + hi * 8;

  // per-lane V LDS read byte offsets (tile-invariant; add CB + dd*4096)
  int vv[4];
#pragma unroll
  for (int i = 0; i < 4; ++i)
    vv[i] = c32 * 128 + (((((i << 1) | hi) ^ (c32 & 7))) << 4);

  // persistent V staging source pointers (advance by 64 u16 per tile)
  const u16* sp[4];
#pragma unroll
  for (int j = 0; j < 4; ++j) {
    const int ch = (wid << 2) | j;
    const int vrow = (ch << 3) + (lane >> 3);
    sp[j] = Vt + ((size_t)(bh * 128 + vrow)) * 2048 +
            (((lane & 7) ^ (vrow & 7)) << 3);
  }

  f32x16 z16;
#pragma unroll
  for (int i = 0; i < 16; ++i) z16[i] = 0.f;
  f32x16 acc[4];
#pragma unroll
  for (int d = 0; d < 4; ++d) acc[d] = z16;
  float L_r = 0.f;

  STAGE_TO(0);
  __syncthreads();

  for (int tt = 0; tt < 16; ++tt) {
    TILE(0, 16384, tt * 2);
    TILE(16384, 0, tt * 2 + 1);
  }

  // ---- epilogue: merge L halves; unnormalized O (bf16) + L to LDS; diff + RMS ----
  L_r += __shfl_xor(L_r, 32);
  u16* Olds = (u16*)smem;                       // [2][64][128]
  float* Lf = (float*)(smem + 32768);           // [2][64]
#pragma unroll
  for (int d = 0; d < 4; ++d)
#pragma unroll
    for (int r = 0; r < 16; ++r) {
      const int row = sg * 32 + (r & 3) + 8 * (r >> 2) + 4 * hi;
      Olds[p * 8192 + row * 128 + d * 32 + c32] = b16(acc[d][r]);
    }
  if (lane < 32) Lf[p * 64 + sg * 32 + c32] = L_r;
  __syncthreads();

  {
    const float lam = lamp[0];
    const int d0 = (tid & 15) * 8;
    float lw[8], lb[8];
#pragma unroll
    for (int j = 0; j < 8; ++j) {
      lw[j] = lnw[d0 + j];
      lb[j] = lnb[d0 + j];
    }
#pragma unroll
    for (int it = 0; it < 4; ++it) {
      const int row = (tid >> 4) + it * 16;
      u16x8 o1 = *(const u16x8*)(Olds + row * 128 + d0);
      u16x8 o2 = *(const u16x8*)(Olds + 8192 + row * 128 + d0);
      float inv1 = 1.f / Lf[row];
      float inv2 = lam / Lf[64 + row];
      float v[8];
      float ss = 0.f;
#pragma unroll
      for (int j = 0; j < 8; ++j) {
        v[j] = bf2f(o1[j]) * inv1 - bf2f(o2[j]) * inv2;
        ss += v[j] * v[j];
      }
      ss += __shfl_xor(ss, 1);
      ss += __shfl_xor(ss, 2);
      ss += __shfl_xor(ss, 4);
      ss += __shfl_xor(ss, 8);
      float rinv = rsqrtf(ss * (1.0f / 128.0f) + 1e-8f);
      u16x8 o;
#pragma unroll
      for (int j = 0; j < 8; ++j)
        o[j] = b16((v[j] * rinv * lw[j] + lb[j]) * ONE_MINUS_LI);
      *(u16x8*)(Oc + (size_t)(b * 2048 + qt * 64 + row) * 1024 + h * 128 + d0) = o;
    }
  }
}

#undef TILE
#undef PACK4
#undef STAGE_TO

extern "C" void kernel_launch(void* const* d_in, const int* in_sizes, int n_in,
                              void* d_out, int out_size, void* d_ws, size_t ws_size,
                              hipStream_t stream) {
  const float* x   = (const float*)d_in[0];
  const float* Wq  = (const float*)d_in[1];
  const float* Wk  = (const float*)d_in[2];
  const float* Wv  = (const float*)d_in[3];
  const float* Wo  = (const float*)d_in[4];
  const float* lq1 = (const float*)d_in[5];
  const float* lk1 = (const float*)d_in[6];
  const float* lq2 = (const float*)d_in[7];
  const float* lk2 = (const float*)d_in[8];
  const float* lnw = (const float*)d_in[9];
  const float* lnb = (const float*)d_in[10];

  char* w = (char*)d_ws;
  size_t off = 0;
  auto alloc = [&](size_t bytes) {
    char* pp = w + off;
    off = (off + bytes + 255) & ~(size_t)255;
    return pp;
  };
  u16* xb   = (u16*)alloc(4096ull * 1024 * 2);
  u16* wqb  = (u16*)alloc(1024ull * 1024 * 2);
  u16* wkb  = (u16*)alloc(1024ull * 1024 * 2);
  u16* wvb  = (u16*)alloc(1024ull * 1024 * 2);
  u16* wob  = (u16*)alloc(1024ull * 1024 * 2);
  u16* Qb   = (u16*)alloc(4096ull * 1024 * 2);
  u16* Kb   = (u16*)alloc(4096ull * 1024 * 2);
  u16* Vt   = (u16*)alloc(4096ull * 1024 * 2);
  u16* Ocb  = (u16*)alloc(4096ull * 1024 * 2);
  float* cosT = (float*)alloc(2048ull * 32 * 4);
  float* sinT = (float*)alloc(2048ull * 32 * 4);
  float* lamp = (float*)alloc(256);

  prep_kernel<<<8449, 256, 0, stream>>>(x, Wq, Wk, Wv, Wo, lq1, lk1, lq2, lk2,
                                        xb, wqb, wkb, wvb, wob, cosT, sinT, lamp);

  // QKV projections: Q/K with fused RoPE (Q pre-scaled), V written transposed
  gemm_qkv_kernel<<<dim3(32, 8, 3), 256, 0, stream>>>(xb, wqb, wkb, wvb,
                                                      Qb, Kb, Vt, cosT, sinT);

  // fused diff flash attention + RMS norm (K-direct de-pipelined, V-only LDS dbuf)
  attn_kernel<<<512, 256, 0, stream>>>(Qb, Kb, Vt, lamp, lnw, lnb, Ocb);

  // output projection (128x64 tiles -> 512 blocks, 2/CU)
  gemm_f32_kernel<<<dim3(32, 16), 256, 0, stream>>>(Ocb, wob, (float*)d_out);
}

// Round 18
// 134.281 us; speedup vs baseline: 1.1151x; 1.1151x over previous
//
#include <hip/hip_runtime.h>

typedef unsigned short u16;
typedef unsigned int u32;
typedef u16 u16x8 __attribute__((ext_vector_type(8)));
typedef u16 u16x4 __attribute__((ext_vector_type(4)));
typedef u32 u32x4 __attribute__((ext_vector_type(4)));
typedef float f32x4 __attribute__((ext_vector_type(4)));
typedef float f32x16 __attribute__((ext_vector_type(16)));
typedef __bf16 bf16x8 __attribute__((ext_vector_type(8)));

#define SCALE_L2E 0.51006972864f  /* 64^-0.25 * log2(e), folded into Q rope */
#define LAMBDA_INIT 0.7836057665316245f
#define ONE_MINUS_LI 0.21639423346837554f

__device__ __forceinline__ u16 b16(float f) {
  return __builtin_bit_cast(u16, (__bf16)f);
}
__device__ __forceinline__ float bf2f(u16 h) {
  unsigned u = ((unsigned)h) << 16;
  return __builtin_bit_cast(float, u);
}
__device__ __forceinline__ u32 pk2(float lo, float hi) {
  return (u32)b16(lo) | ((u32)b16(hi) << 16);
}
__device__ __forceinline__ f32x4 mfma16(bf16x8 a, bf16x8 b, f32x4 c) {
  return __builtin_amdgcn_mfma_f32_16x16x32_bf16(a, b, c, 0, 0, 0);
}
__device__ __forceinline__ f32x16 mfma32(bf16x8 a, bf16x8 b, f32x16 c) {
  return __builtin_amdgcn_mfma_f32_32x32x16_bf16(a, b, c, 0, 0, 0);
}
// v_permlane32_swap: only with operands holding DISTINCT values (same-value
// operands may be register-coalesced -> degenerate half-rotate; r7 bug).
// NOTE (r13): extra mfma consumers of permlane-built P broke numerics; do not retry.
// NOTE (r16): cross-iteration K-register prefetch pipeline broke numerics.
// NOTE (r17): K-direct-from-global (de-pipelined) is correct but SLOWER (exposed
// L2 latency per tile; attn 70->85us). LDS-staged K is the right structure here.
__device__ __forceinline__ void plswapu(u32& a, u32& b) {
  asm("v_permlane32_swap_b32 %0, %1" : "+v"(a), "+v"(b));
}
// async global->LDS, 16B/lane; LDS dest = wave-uniform base + lane*16
__device__ __forceinline__ void gld16(const void* g, void* l) {
  __builtin_amdgcn_global_load_lds(
      (const __attribute__((address_space(1))) unsigned int*)g,
      (__attribute__((address_space(3))) unsigned int*)l, 16, 0, 0);
}

// ---------------- fused prep: f32->bf16 converts + RoPE table + lambda ----------------
__global__ void prep_kernel(const float* __restrict__ x, const float* __restrict__ Wq,
                            const float* __restrict__ Wk, const float* __restrict__ Wv,
                            const float* __restrict__ Wo,
                            const float* __restrict__ lq1, const float* __restrict__ lk1,
                            const float* __restrict__ lq2, const float* __restrict__ lk2,
                            u16* __restrict__ xb, u16* __restrict__ wqb, u16* __restrict__ wkb,
                            u16* __restrict__ wvb, u16* __restrict__ wob,
                            float* __restrict__ cosT, float* __restrict__ sinT,
                            float* __restrict__ lamp) {
  const int bid = blockIdx.x, tid = threadIdx.x;
  if (bid < 8192) {
    const float* src; u16* dst; int off;
    if (bid < 4096) { src = x; dst = xb; off = bid; }
    else {
      const int wsel = (bid - 4096) >> 10;
      off = (bid - 4096) & 1023;
      src = wsel == 0 ? Wq : wsel == 1 ? Wk : wsel == 2 ? Wv : Wo;
      dst = wsel == 0 ? wqb : wsel == 1 ? wkb : wsel == 2 ? wvb : wob;
    }
    const size_t i = (size_t)off * 256 + tid;
    f32x4 v = *(const f32x4*)(src + i * 4);
    u16x4 o;
    o[0] = b16(v[0]); o[1] = b16(v[1]); o[2] = b16(v[2]); o[3] = b16(v[3]);
    *(u16x4*)(dst + i * 4) = o;
  } else if (bid < 8448) {
    const int i = (bid - 8192) * 256 + tid;   // 0..65535 = [s=2048][fi=32]
    const int fi = i & 31, t = i >> 5;
    float invf = expf(-(float)fi * 0.2878231366242558f);
    float f = (float)t * invf;
    cosT[i] = cosf(f);
    sinT[i] = sinf(f);
  } else if (tid < 64) {
    int l = tid;
    float a = lq1[l] * lk1[l];
    float bb = lq2[l] * lk2[l];
#pragma unroll
    for (int m = 1; m < 64; m <<= 1) {
      a += __shfl_xor(a, m);
      bb += __shfl_xor(bb, m);
    }
    if (l == 0) lamp[0] = expf(a) - expf(bb) + LAMBDA_INIT;
  }
}

// ---------------- GEMM C = A @ B^T via global_load_lds + XOR swizzle ----------------
// MODE 0: bf16 row-major out; 1: f32 row-major out; 2: bf16 V-transposed out
//   (MODE 2: Vt[(b*8 + col/128)*128 + col%128][s], s = global row)
// MODE 3: bf16 row-major out with fused interleaved RoPE (pair = col^1 = lane c^1,
//   partner value via __shfl_xor on f32 acc; cos/sin scaled by ropeScale).
template<int MODE, int BN>
__device__ __forceinline__ void gemm_body(const u16* __restrict__ A, const u16* __restrict__ Bm,
                                          void* __restrict__ C, int M, int N, int K,
                                          const float* __restrict__ cosT,
                                          const float* __restrict__ sinT, float ropeScale) {
  __shared__ __align__(1024) u16 As[128][64];
  __shared__ __align__(1024) u16 Bs[BN][64];
  constexpr int NF = BN / 32;          // n-frags per wave
  constexpr int JL = (16 + BN / 8) / 4; // staged chunks per wave
  const int tid = threadIdx.x;
  const int lane = tid & 63, wid = tid >> 6;
  const int wr = wid >> 1, wc = wid & 1;
  const int c = lane & 15, g = lane >> 4;
  const int bm = blockIdx.x * 128, bn = blockIdx.y * BN;
  const int srow = lane >> 3;          // 0..7 (row within 8-row chunk)
  const int scol = lane & 7;
  f32x4 acc[4][NF];
#pragma unroll
  for (int m = 0; m < 4; ++m)
#pragma unroll
    for (int n = 0; n < NF; ++n) acc[m][n] = (f32x4){0.f, 0.f, 0.f, 0.f};

  for (int k0 = 0; k0 < K; k0 += 64) {
#pragma unroll
    for (int j = 0; j < JL; ++j) {
      const int cid = wid * JL + j;       // wave-uniform chunk id
      if (cid < 16) {
        const int row = (cid << 3) + srow;
        gld16(A + (size_t)(bm + row) * K + k0 + ((scol ^ srow) << 3), &As[cid << 3][0]);
      } else {
        const int ch = cid - 16;
        const int row = (ch << 3) + srow;
        gld16(Bm + (size_t)(bn + row) * K + k0 + ((scol ^ srow) << 3), &Bs[ch << 3][0]);
      }
    }
    __syncthreads();
#pragma unroll
    for (int kk = 0; kk < 2; ++kk) {
      bf16x8 af[4], bfm[NF];
#pragma unroll
      for (int m = 0; m < 4; ++m)
        af[m] = __builtin_bit_cast(bf16x8,
            *(const u16x8*)(&As[wr * 64 + m * 16 + c][(((kk << 2) | g) ^ (c & 7)) << 3]));
#pragma unroll
      for (int n = 0; n < NF; ++n)
        bfm[n] = __builtin_bit_cast(bf16x8,
            *(const u16x8*)(&Bs[wc * (BN / 2) + n * 16 + c][(((kk << 2) | g) ^ (c & 7)) << 3]));
#pragma unroll
      for (int m = 0; m < 4; ++m)
#pragma unroll
        for (int n = 0; n < NF; ++n)
          acc[m][n] = mfma16(af[m], bfm[n], acc[m][n]);
    }
    __syncthreads();
  }
#pragma unroll
  for (int m = 0; m < 4; ++m)
#pragma unroll
    for (int n = 0; n < NF; ++n) {
      const int col = bn + wc * (BN / 2) + n * 16 + c;
      const int row0 = bm + wr * 64 + m * 16 + g * 4;
      if constexpr (MODE == 2) {
        const int bI = row0 >> 11, s0 = row0 & 2047;
        u16x4 pk;
#pragma unroll
        for (int r = 0; r < 4; ++r) pk[r] = b16(acc[m][n][r]);
        *(u16x4*)((u16*)C + ((size_t)(bI * 8 + (col >> 7)) * 128 + (col & 127)) * 2048 + s0) = pk;
      } else if constexpr (MODE == 3) {
        const int dcol = col & 63;
        const int fi = dcol >> 1;
#pragma unroll
        for (int r = 0; r < 4; ++r) {
          float v = acc[m][n][r];
          float vp = __shfl_xor(v, 1);          // partner col^1 = lane c^1
          const int s = (row0 + r) & 2047;
          float cc = cosT[s * 32 + fi] * ropeScale;
          float sn = sinT[s * 32 + fi] * ropeScale;
          float ov = (dcol & 1) ? (v * cc + vp * sn) : (v * cc - vp * sn);
          ((u16*)C)[(size_t)(row0 + r) * N + col] = b16(ov);
        }
      } else {
#pragma unroll
        for (int r = 0; r < 4; ++r) {
          if constexpr (MODE == 1) ((float*)C)[(size_t)(row0 + r) * N + col] = acc[m][n][r];
          else ((u16*)C)[(size_t)(row0 + r) * N + col] = b16(acc[m][n][r]);
        }
      }
    }
}

__global__ __launch_bounds__(256) void gemm_qkv_kernel(
    const u16* __restrict__ A,
    const u16* __restrict__ B0, const u16* __restrict__ B1, const u16* __restrict__ B2,
    u16* __restrict__ C0, u16* __restrict__ C1, u16* __restrict__ C2,
    const float* __restrict__ cosT, const float* __restrict__ sinT) {
  if (blockIdx.z == 0)
    gemm_body<3, 128>(A, B0, C0, 4096, 1024, 1024, cosT, sinT, SCALE_L2E);  // Q: rope+scale
  else if (blockIdx.z == 1)
    gemm_body<3, 128>(A, B1, C1, 4096, 1024, 1024, cosT, sinT, 1.0f);       // K: rope
  else
    gemm_body<2, 128>(A, B2, C2, 4096, 1024, 1024, nullptr, nullptr, 0.f);  // V: transpose
}

__global__ __launch_bounds__(256) void gemm_f32_kernel(const u16* __restrict__ A,
                                                       const u16* __restrict__ Bm,
                                                       float* __restrict__ C) {
  gemm_body<1, 64>(A, Bm, C, 4096, 1024, 1024, nullptr, nullptr, 0.f);
}

// ---------------- fused flash diff-attention (v15: r15 + deferred L merge) ----------------
// r15-verified structure (KVBLK=64, 32x32 MFMA, in-reg P, max-free log2 softmax,
// LDS-staged K+V dbuf, strength-reduced addressing). Single change vs r15:
// the per-tile L cross-half __shfl_xor(32) is deferred to one epilogue merge
// (L is a pure linear sum; correctness of deferral verified by r17's pass).
#define STAGE_TO(NB)                                                           \
  {                                                                            \
    _Pragma("unroll")                                                          \
    for (int j = 0; j < 8; ++j) {                                              \
      const int cid = (wid << 3) | j;                                          \
      gld16(sp[j], smem + (NB) + cid * 1024);                                  \
      sp[j] += (cid < 16) ? 65536 : 64;                                        \
    }                                                                          \
  }

#define PACK4(PE, PA0, PA1)                                                    \
  {                                                                            \
    u32 w0 = pk2(PE[0], PE[1]),   w1 = pk2(PE[2], PE[3]);                      \
    u32 w2 = pk2(PE[4], PE[5]),   w3 = pk2(PE[6], PE[7]);                      \
    u32 w4 = pk2(PE[8], PE[9]),   w5 = pk2(PE[10], PE[11]);                    \
    u32 w6 = pk2(PE[12], PE[13]), w7 = pk2(PE[14], PE[15]);                    \
    plswapu(w0, w2); plswapu(w1, w3);                                          \
    plswapu(w4, w6); plswapu(w5, w7);                                          \
    u32x4 pw0, pw1;                                                            \
    pw0[0] = w0; pw0[1] = w1; pw0[2] = w2; pw0[3] = w3;                        \
    pw1[0] = w4; pw1[1] = w5; pw1[2] = w6; pw1[3] = w7;                        \
    PA0 = __builtin_bit_cast(bf16x8, pw0);                                     \
    PA1 = __builtin_bit_cast(bf16x8, pw1);                                     \
  }

#define TILE(CB, NB, T)                                                        \
  {                                                                            \
    if ((T) < 31) STAGE_TO(NB);                                                \
    f32x16 sacc[2];                                                            \
    _Pragma("unroll")                                                          \
    for (int s32 = 0; s32 < 2; ++s32) {                                        \
      bf16x8 kf = __builtin_bit_cast(bf16x8,                                   \
          *(const u16x8*)(smem + (CB) + s32 * 4096 + kv[0]));                  \
      sacc[s32] = mfma32(kf, qf[0], z16);                                      \
      _Pragma("unroll")                                                        \
      for (int ds = 1; ds < 4; ++ds) {                                         \
        kf = __builtin_bit_cast(bf16x8,                                        \
            *(const u16x8*)(smem + (CB) + s32 * 4096 + kv[ds]));               \
        sacc[s32] = mfma32(kf, qf[ds], sacc[s32]);                             \
      }                                                                        \
    }                                                                          \
    float pe0[16], pe1[16];                                                    \
    float sA = 0.f, sB = 0.f, sC = 0.f, sD = 0.f;                              \
    _Pragma("unroll")                                                          \
    for (int i = 0; i < 16; i += 2) {                                          \
      pe0[i] = __builtin_amdgcn_exp2f(sacc[0][i]);                             \
      sA += pe0[i];                                                            \
      pe0[i + 1] = __builtin_amdgcn_exp2f(sacc[0][i + 1]);                     \
      sB += pe0[i + 1];                                                        \
      pe1[i] = __builtin_amdgcn_exp2f(sacc[1][i]);                             \
      sC += pe1[i];                                                            \
      pe1[i + 1] = __builtin_amdgcn_exp2f(sacc[1][i + 1]);                     \
      sD += pe1[i + 1];                                                        \
    }                                                                          \
    L_r += (sA + sB) + (sC + sD);                                              \
    bf16x8 pa[4];                                                              \
    PACK4(pe0, pa[0], pa[1]);                                                  \
    PACK4(pe1, pa[2], pa[3]);                                                  \
    _Pragma("unroll")                                                          \
    for (int dd = 0; dd < 4; ++dd) {                                           \
      _Pragma("unroll")                                                        \
      for (int ks = 0; ks < 4; ++ks) {                                         \
        bf16x8 vf = __builtin_bit_cast(bf16x8,                                 \
            *(const u16x8*)(smem + (CB) + dd * 4096 + vv[ks]));                \
        acc[dd] = mfma32(pa[ks], vf, acc[dd]);                                 \
      }                                                                        \
    }                                                                          \
    __syncthreads();                                                           \
  }

__global__ __launch_bounds__(256, 2) void attn_kernel(
    const u16* __restrict__ Qb, const u16* __restrict__ Kb, const u16* __restrict__ Vt,
    const float* __restrict__ lamp, const float* __restrict__ lnw, const float* __restrict__ lnb,
    u16* __restrict__ Oc) {
  // buffer q (q=0,1) at smem + q*32768: K[2][64][64] (16KB) @ +0, V[128][64] (16KB) @ +16384
  // epilogue overlay: O[2][64][128] u16 (32KB) @ 0 + L[2][64] f32 @ +32768
  __shared__ __align__(1024) char smem[65536];
  const int tid = threadIdx.x;
  const int lane = tid & 63;
  const int wid = tid >> 6;            // 0..3
  const int c32 = lane & 31, hi = lane >> 5;
  const int p = wid >> 1, sg = wid & 1;

  const int B = blockIdx.x;
  const int xcd = B & 7, bidx = B >> 3;
  const int bh = xcd * 2 + (bidx >> 5);
  const int qt = bidx & 31;
  const int b = bh >> 3, h = bh & 7;
  const int head2 = 2 * h + p;

  // Q fragments: lane owns q-row qrow; qf[ds] covers d = ds*16 + hi*8 .. +8
  const int qrow = qt * 64 + sg * 32 + c32;
  bf16x8 qf[4];
#pragma unroll
  for (int ds = 0; ds < 4; ++ds)
    qf[ds] = __builtin_bit_cast(bf16x8,
        *(const u16x8*)(Qb + ((size_t)(b * 2048 + qrow) * 16 + head2) * 64 + ds * 16 + hi * 8));

  // per-lane LDS read byte offsets (tile-invariant)
  int kv[4], vv[4];
#pragma unroll
  for (int i = 0; i < 4; ++i) {
    const int swz = ((((i << 1) | hi) ^ (c32 & 7)) << 4);
    kv[i] = p * 8192 + c32 * 128 + swz;
    vv[i] = 16384 + c32 * 128 + swz;
  }

  // persistent staging source pointers (advance by constant stride per tile)
  const u16* sp[8];
#pragma unroll
  for (int j = 0; j < 8; ++j) {
    const int cid = (wid << 3) | j;
    if (cid < 16) {
      const int pp = cid >> 3, ch = cid & 7;
      const int krow = (ch << 3) + (lane >> 3);
      sp[j] = Kb + ((size_t)(b * 2048 + krow) * 16 + 2 * h + pp) * 64 +
              (((lane & 7) ^ (krow & 7)) << 3);
    } else {
      const int ch = cid & 15;
      const int vrow = (ch << 3) + (lane >> 3);
      sp[j] = Vt + ((size_t)(bh * 128 + vrow)) * 2048 +
              (((lane & 7) ^ (vrow & 7)) << 3);
    }
  }

  f32x16 z16;
#pragma unroll
  for (int i = 0; i < 16; ++i) z16[i] = 0.f;
  f32x16 acc[4];
#pragma unroll
  for (int d = 0; d < 4; ++d) acc[d] = z16;
  float L_r = 0.f;

  STAGE_TO(0);
  __syncthreads();

  for (int tt = 0; tt < 16; ++tt) {
    TILE(0, 32768, tt * 2);
    TILE(32768, 0, tt * 2 + 1);
  }

  // ---- epilogue: merge L halves; unnormalized O (bf16) + L to LDS; diff + RMS ----
  L_r += __shfl_xor(L_r, 32);
  u16* Olds = (u16*)smem;                       // [2][64][128]
  float* Lf = (float*)(smem + 32768);           // [2][64]
#pragma unroll
  for (int d = 0; d < 4; ++d)
#pragma unroll
    for (int r = 0; r < 16; ++r) {
      const int row = sg * 32 + (r & 3) + 8 * (r >> 2) + 4 * hi;
      Olds[p * 8192 + row * 128 + d * 32 + c32] = b16(acc[d][r]);
    }
  if (lane < 32) Lf[p * 64 + sg * 32 + c32] = L_r;
  __syncthreads();

  {
    const float lam = lamp[0];
    const int d0 = (tid & 15) * 8;
    float lw[8], lb[8];
#pragma unroll
    for (int j = 0; j < 8; ++j) {
      lw[j] = lnw[d0 + j];
      lb[j] = lnb[d0 + j];
    }
#pragma unroll
    for (int it = 0; it < 4; ++it) {
      const int row = (tid >> 4) + it * 16;
      u16x8 o1 = *(const u16x8*)(Olds + row * 128 + d0);
      u16x8 o2 = *(const u16x8*)(Olds + 8192 + row * 128 + d0);
      float inv1 = 1.f / Lf[row];
      float inv2 = lam / Lf[64 + row];
      float v[8];
      float ss = 0.f;
#pragma unroll
      for (int j = 0; j < 8; ++j) {
        v[j] = bf2f(o1[j]) * inv1 - bf2f(o2[j]) * inv2;
        ss += v[j] * v[j];
      }
      ss += __shfl_xor(ss, 1);
      ss += __shfl_xor(ss, 2);
      ss += __shfl_xor(ss, 4);
      ss += __shfl_xor(ss, 8);
      float rinv = rsqrtf(ss * (1.0f / 128.0f) + 1e-8f);
      u16x8 o;
#pragma unroll
      for (int j = 0; j < 8; ++j)
        o[j] = b16((v[j] * rinv * lw[j] + lb[j]) * ONE_MINUS_LI);
      *(u16x8*)(Oc + (size_t)(b * 2048 + qt * 64 + row) * 1024 + h * 128 + d0) = o;
    }
  }
}

#undef TILE
#undef PACK4
#undef STAGE_TO

extern "C" void kernel_launch(void* const* d_in, const int* in_sizes, int n_in,
                              void* d_out, int out_size, void* d_ws, size_t ws_size,
                              hipStream_t stream) {
  const float* x   = (const float*)d_in[0];
  const float* Wq  = (const float*)d_in[1];
  const float* Wk  = (const float*)d_in[2];
  const float* Wv  = (const float*)d_in[3];
  const float* Wo  = (const float*)d_in[4];
  const float* lq1 = (const float*)d_in[5];
  const float* lk1 = (const float*)d_in[6];
  const float* lq2 = (const float*)d_in[7];
  const float* lk2 = (const float*)d_in[8];
  const float* lnw = (const float*)d_in[9];
  const float* lnb = (const float*)d_in[10];

  char* w = (char*)d_ws;
  size_t off = 0;
  auto alloc = [&](size_t bytes) {
    char* pp = w + off;
    off = (off + bytes + 255) & ~(size_t)255;
    return pp;
  };
  u16* xb   = (u16*)alloc(4096ull * 1024 * 2);
  u16* wqb  = (u16*)alloc(1024ull * 1024 * 2);
  u16* wkb  = (u16*)alloc(1024ull * 1024 * 2);
  u16* wvb  = (u16*)alloc(1024ull * 1024 * 2);
  u16* wob  = (u16*)alloc(1024ull * 1024 * 2);
  u16* Qb   = (u16*)alloc(4096ull * 1024 * 2);
  u16* Kb   = (u16*)alloc(4096ull * 1024 * 2);
  u16* Vt   = (u16*)alloc(4096ull * 1024 * 2);
  u16* Ocb  = (u16*)alloc(4096ull * 1024 * 2);
  float* cosT = (float*)alloc(2048ull * 32 * 4);
  float* sinT = (float*)alloc(2048ull * 32 * 4);
  float* lamp = (float*)alloc(256);

  prep_kernel<<<8449, 256, 0, stream>>>(x, Wq, Wk, Wv, Wo, lq1, lk1, lq2, lk2,
                                        xb, wqb, wkb, wvb, wob, cosT, sinT, lamp);

  // QKV projections: Q/K with fused RoPE (Q pre-scaled), V written transposed
  gemm_qkv_kernel<<<dim3(32, 8, 3), 256, 0, stream>>>(xb, wqb, wkb, wvb,
                                                      Qb, Kb, Vt, cosT, sinT);

  // fused diff flash attention + RMS norm (KVBLK=64, 32x32 MFMA, max-free softmax)
  attn_kernel<<<512, 256, 0, stream>>>(Qb, Kb, Vt, lamp, lnw, lnb, Ocb);

  // output projection (128x64 tiles -> 512 blocks, 2/CU)
  gemm_f32_kernel<<<dim3(32, 16), 256, 0, stream>>>(Ocb, wob, (float*)d_out);
}